// Round 4
// baseline (174.474 us; speedup 1.0000x reference)
//
#include <hip/hip_runtime.h>
#include <math.h>

#define TILE_W 64
#define TILE_H 4
#define HALO 4
#define TWX 72
#define TWY 12
#define NST (TWX*TWY)   // 864
#define QIW 528         // quad image row stride (float4 elems)
#define QIH 520

#if __has_builtin(__builtin_amdgcn_fractf)
#define FRACTF(x) __builtin_amdgcn_fractf(x)
#else
#define FRACTF(x) ((x) - floorf(x))
#endif
#if __has_builtin(__builtin_amdgcn_exp2f)
#define EXP2F(x) __builtin_amdgcn_exp2f(x)
#else
#define EXP2F(x) exp2f(x)
#endif
#if __has_builtin(__builtin_amdgcn_logf)
#define LOG2F(x) __builtin_amdgcn_logf(x)
#else
#define LOG2F(x) log2f(x)
#endif

// tbl layout (floats):
// [0..23] cos_q  [24..47] sin_q  [48..71] cos_q*SC  [72..95] sin_q*SC
// [96..103] wn_norm*log2e  [104] irt*log2e  [105] gamma  [106] gain
// [107] dense flag (int)  [108..139] sparse tap w [4][8]  [140..171] sparse tap off (int)
// [172] fastconv ok flag (int)  [180..183] per-bank equal weight
__global__ __launch_bounds__(64) void gp_setup(const float* __restrict__ gain,
                                               const float* __restrict__ lrt,
                                               const float* __restrict__ rlg,
                                               const float* __restrict__ Wb,
                                               float* __restrict__ tbl) {
  int t = threadIdx.x;
  __shared__ float wtmp[8];
  if (t < 8) {
    float tn = (float)(t + 1) * 0.375f;
    wtmp[t] = expf(-0.5f * tn * tn);
  }
  if (t < 24) {
    float th = (6.283185307179586f * (float)t) / 24.0f;
    float c = cosf(th), s = sinf(th);
    const float sc = (float)(512.0 / 511.0);
    tbl[t] = c; tbl[24 + t] = s; tbl[48 + t] = c * sc; tbl[72 + t] = s * sc;
  }
  __syncthreads();
  if (t == 0) {
    const float L2E = 1.44269504088896340736f;
    float sum = 0.f;
    for (int n = 0; n < 8; ++n) sum += wtmp[n];
    for (int n = 0; n < 8; ++n) tbl[96 + n] = (wtmp[n] / sum) * L2E;
    float rt = expf(lrt[0]);
    rt = fminf(fmaxf(rt, 0.001f), 2.0f);
    float sg = 1.0f / (1.0f + expf(-rlg[0]));
    float rho = sg * 0.95f + 0.05f;
    tbl[104] = (1.0f / rt) * L2E;
    tbl[105] = 1.0f / (rho + 1e-8f);
    tbl[106] = fmaxf(gain[0], 0.001f);

    int* ti = (int*)tbl;
    int dense = 0;
    for (int o = 0; o < 4; ++o) {
      int cnt = 0;
      for (int k = 0; k < 49; ++k) {
        float w = Wb[o * 49 + k];
        if (w != 0.0f) {
          if (cnt < 8) {
            int kj = k / 7, ki = k - kj * 7;
            tbl[108 + o * 8 + cnt] = w;
            ti[140 + o * 8 + cnt] = kj * TWX + ki;
          }
          cnt++;
        }
      }
      if (cnt > 8) dense = 1;
      for (int c2 = cnt; c2 < 8; ++c2) { tbl[108 + o * 8 + c2] = 0.f; ti[140 + o * 8 + c2] = 0; }
    }
    ti[107] = dense;

    const int K0[7] = {14,15,23,24,25,33,34};
    const int K1[7] = {2,9,17,24,31,39,46};
    const int K2[7] = {4,11,17,24,31,37,44};
    const int K3[7] = {19,20,23,24,25,28,29};
    const int* KK[4] = {K0,K1,K2,K3};
    int ok = 1;
    for (int o = 0; o < 4; ++o) {
      float w0v = Wb[o * 49 + KK[o][0]];
      if (w0v == 0.f) ok = 0;
      unsigned long long mask = 0;
      for (int t2 = 0; t2 < 7; ++t2) mask |= 1ull << KK[o][t2];
      for (int k = 0; k < 49; ++k) {
        float w = Wb[o * 49 + k];
        int nz = (w != 0.f);
        int want = (int)((mask >> k) & 1ull);
        if (nz != want) ok = 0;
        if (nz && w != w0v) ok = 0;
      }
      tbl[180 + o] = w0v;
    }
    ti[172] = ok;
  }
}

// Prepass: pre-differenced bilinear quads, Fm staged in LDS (x read once-ish).
__global__ __launch_bounds__(256) void gp_quad2(const float* __restrict__ x,
                                                float4* __restrict__ qimg) {
  __shared__ float F[5][66];
  const int tid = threadIdx.x;
  const int tx = tid & 63, ty = tid >> 6;
  const int x0 = blockIdx.x * 64;
  const int y0 = blockIdx.y * 4;
  const int b = blockIdx.z;
  const float* __restrict__ x0p = x + (size_t)b * 2 * 512 * 512;
  const float* __restrict__ x1p = x0p + 512 * 512;

  // Stage Fm for region X = x0-4 .. x0+60 (65 cols), Y = y0-4 .. y0 (5 rows).
  #pragma unroll
  for (int it = 0; it < 2; ++it) {
    int idx = tid + it * 256;
    if (idx < 330) {
      int r = idx / 66, c = idx - r * 66;
      int X = x0 - 4 + c, Y = y0 - 4 + r;
      float f = 0.f;
      if ((unsigned)X < 512u && (unsigned)Y < 512u) {
        size_t o = (size_t)Y * 512 + X;
        float a = x0p[o], bv = x1p[o];
        f = sqrtf(a * a + bv * bv);
      }
      F[r][c] = f;
    }
  }
  __syncthreads();

  int xx = x0 + tx;
  if (xx >= QIH) return;
  int yy = y0 + ty;
  float f00 = F[ty][tx],     f01 = F[ty][tx + 1];
  float f10 = F[ty + 1][tx], f11 = F[ty + 1][tx + 1];
  qimg[((size_t)b * QIH + yy) * QIW + xx] =
      make_float4(f00, f01 - f00, f10 - f00, (f11 - f10) - (f01 - f00));
}

// Main: paired angles — angle q (LDS window) + angle q+12 (VMEM quad image,
// L1-resident window) run concurrently with independent accumulator chains.
__global__ __launch_bounds__(256) void gp_main3(const float* __restrict__ x,
                                                const float4* __restrict__ qimg,
                                                const float* __restrict__ Wb,
                                                const float* __restrict__ cen,
                                                const float* __restrict__ tbl,
                                                float* __restrict__ out) {
  __shared__ float4 Qd[NST];
  __shared__ float  Sm[NST];

  const int tid = threadIdx.x;
  const int tx = tid & 63, ty = tid >> 6;
  int wg = blockIdx.x;
  int swz = (wg & 7) * 1024 + (wg >> 3);   // XCD k -> batch k (4.4MB ~ L2)
  int bx = swz & 7;
  int by = (swz >> 3) & 127;
  int b  = swz >> 10;

  const int bx0 = bx * 64 - HALO, by0 = by * 4 - HALO;
  const float* __restrict__ x0p = x + (size_t)b * 2 * 512 * 512;
  const float* __restrict__ x1p = x0p + 512 * 512;
  const float4* __restrict__ qb = qimg + ((size_t)b * QIH + (by * 4)) * QIW + (bx * 64);

  #pragma unroll
  for (int it = 0; it < 4; ++it) {
    int idx = tid + it * 256;
    int i2 = (idx < NST) ? idx : (NST - 1);
    int r = i2 / TWX, c = i2 - r * TWX;
    if (idx < NST) Qd[idx] = qb[r * QIW + c];
  }
  #pragma unroll
  for (int it = 0; it < 4; ++it) {
    int idx = tid + it * 256;
    if (idx < NST) {
      int r = idx / TWX, c = idx - r * TWX;
      int gy = by0 + r, gx = bx0 + c;
      float a = 0.f, bv = 0.f;
      if ((unsigned)gx < 512u && (unsigned)gy < 512u) {
        size_t o = (size_t)gy * 512 + gx;
        a = x0p[o]; bv = x1p[o];
      }
      Sm[idx] = a + bv;
    }
  }
  __syncthreads();

  const int gi = bx * 64 + tx;
  const int gj = by * 4 + ty;
  const float SC = (float)(512.0 / 511.0);
  const float axl = fmaf((float)gi, SC, -0.5f) - (float)bx0;  // window coords, >0
  const float ayl = fmaf((float)gj, SC, -0.5f) - (float)by0;

  float wn[8];
  #pragma unroll
  for (int n = 0; n < 8; ++n) wn[n] = tbl[96 + n];   // uniform -> SGPR

  float SYa = 0.f, CXa = 0.f, SYb = 0.f, CXb = 0.f;
  for (int a = 0; a < 12; ++a) {
    const int qA = a, qB = a + 12;
    const float csA = tbl[48 + qA], snA = tbl[72 + qA];
    const float csB = tbl[48 + qB], snB = tbl[72 + qB];

    // Group B: issue all 8 VMEM loads up front (consumed below).
    float4 vB[8]; float fxB[8], fyB[8];
    #pragma unroll
    for (int n = 0; n < 8; ++n) {
      float tn = 0.375f * (float)(n + 1);
      float px = fmaf(-csB, tn, axl);
      float py = fmaf(-snB, tn, ayl);
      int ix = (int)px, iy = (int)py;
      fxB[n] = FRACTF(px); fyB[n] = FRACTF(py);
      vB[n] = qb[iy * QIW + ix];
    }

    float eA = 0.f, eB = 0.f;
    #pragma unroll
    for (int n = 0; n < 8; ++n) {
      // Group A (LDS)
      float tn = 0.375f * (float)(n + 1);
      float px = fmaf(-csA, tn, axl);
      float py = fmaf(-snA, tn, ayl);
      int ix = (int)px, iy = (int)py;
      float fx = FRACTF(px), fy = FRACTF(py);
      float4 v = Qd[iy * TWX + ix];
      float sA = fmaf(fy, fmaf(fx, v.w, v.z), fmaf(fx, v.y, v.x));
      eA = fmaf(wn[n], sA, eA);
      // Group B (VMEM, prefetched)
      float4 u = vB[n];
      float sB = fmaf(fyB[n], fmaf(fxB[n], u.w, u.z), fmaf(fxB[n], u.y, u.x));
      eB = fmaf(wn[n], sB, eB);
    }
    float ea = EXP2F(eA), eb = EXP2F(eB);
    SYa = fmaf(ea, tbl[24 + qA], SYa);
    CXa = fmaf(ea, tbl[qA], CXa);
    SYb = fmaf(eb, tbl[24 + qB], SYb);
    CXb = fmaf(eb, tbl[qB], CXb);
  }
  float SY = SYa + SYb, CX = CXa + CXb;

  // Conv: verified line-mask fast path (equal weights, shared center triples).
  const int* ti = (const int*)tbl;
  const int ccen = (ty + 4) * TWX + tx + 4;
  float a0, a1, a2, a3;
  if (ti[172]) {
    float sCt = Sm[ccen];
    float H3 = (Sm[ccen - 1] + sCt) + Sm[ccen + 1];
    float V3 = (Sm[ccen - TWX] + sCt) + Sm[ccen + TWX];
    a0 = tbl[180] * (H3 + ((Sm[ccen - 75] + Sm[ccen - 74]) + (Sm[ccen + 74] + Sm[ccen + 75])));
    a1 = tbl[181] * (V3 + ((Sm[ccen - 217] + Sm[ccen - 145]) + (Sm[ccen + 145] + Sm[ccen + 217])));
    a2 = tbl[182] * (V3 + ((Sm[ccen - 215] + Sm[ccen - 143]) + (Sm[ccen + 143] + Sm[ccen + 215])));
    a3 = tbl[183] * (H3 + ((Sm[ccen - 70] + Sm[ccen - 69]) + (Sm[ccen + 69] + Sm[ccen + 70])));
  } else {
    a0 = a1 = a2 = a3 = 0.f;
    for (int kj = 0; kj < 7; ++kj)
      for (int ki = 0; ki < 7; ++ki) {
        float s = Sm[(ty + 1 + kj) * TWX + (tx + 1 + ki)];
        int k = kj * 7 + ki;
        a0 = fmaf(s, Wb[k], a0); a1 = fmaf(s, Wb[49 + k], a1);
        a2 = fmaf(s, Wb[98 + k], a2); a3 = fmaf(s, Wb[147 + k], a3);
      }
  }

  const float TP  = 6.283185307179586f;
  const float PIF = 3.14159265358979323846f;
  const float HP  = 1.57079632679489661923f;
  float hat = atan2f(SY, CX);
  float r1 = hat + TP;
  r1 = (r1 >= TP) ? (r1 - TP) : r1;
  float theta = (r1 >= PIF) ? (r1 - PIF) : r1;

  const float irt2  = tbl[104];
  const float gamma = tbl[105];
  const float gainc = tbl[106];

  float dist[4];
  #pragma unroll
  for (int o = 0; o < 4; ++o) {
    float d = theta - cen[o] + HP;
    d -= (d >= PIF) ? PIF : 0.f;
    d += (d < 0.f) ? PIF : 0.f;
    dist[o] = fabsf(d - HP);
  }
  float mn = fminf(fminf(dist[0], dist[1]), fminf(dist[2], dist[3]));
  float m2 = mn * irt2;
  float eo[4], Z = 0.f;
  #pragma unroll
  for (int o = 0; o < 4; ++o) { eo[o] = EXP2F(fmaf(-irt2, dist[o], m2)); Z += eo[o]; }
  float invZ = 1.0f / Z;
  float sh[4], Zs = 0.f;
  #pragma unroll
  for (int o = 0; o < 4; ++o) {
    sh[o] = EXP2F(gamma * LOG2F(fmaf(eo[o], invZ, 1e-12f)));
    Zs += sh[o];
  }
  float wsi = 1.0f / (Zs + 1e-8f);
  float ov = (a0 * sh[0] + a1 * sh[1] + a2 * sh[2] + a3 * sh[3]) * wsi;

  out[((size_t)b * 512 + gj) * 512 + gi] = gainc * ov;
}

// Fallback (ws too small): Round-2 kernel verbatim (proven 146us path).
__global__ __launch_bounds__(256) void gp_main_fb(const float* __restrict__ x,
                                                  const float* __restrict__ Wb,
                                                  const float* __restrict__ cen,
                                                  const float* __restrict__ tbl,
                                                  float* __restrict__ out) {
  __shared__ float  Fm[NST];
  __shared__ float  Sm[NST];
  __shared__ float4 Qd[NST];
  const int tx = threadIdx.x;
  const int ty = threadIdx.y;
  const int tid = ty * 64 + tx;
  const int bx0 = blockIdx.x * TILE_W - HALO;
  const int by0 = blockIdx.y * TILE_H - HALO;
  const int b = blockIdx.z;
  const float* __restrict__ x0p = x + (size_t)b * 2 * 512 * 512;
  const float* __restrict__ x1p = x0p + 512 * 512;
  #pragma unroll
  for (int it = 0; it < 4; ++it) {
    int idx = tid + it * 256;
    if (idx < NST) {
      int r = idx / TWX, c = idx - r * TWX;
      int gy = by0 + r, gx = bx0 + c;
      float a = 0.f, bv = 0.f;
      if ((unsigned)gx < 512u && (unsigned)gy < 512u) {
        size_t o = (size_t)gy * 512 + gx;
        a = x0p[o]; bv = x1p[o];
      }
      Fm[idx] = sqrtf(a * a + bv * bv);
      Sm[idx] = a + bv;
    }
  }
  __syncthreads();
  #pragma unroll
  for (int it = 0; it < 4; ++it) {
    int idx = tid + it * 256;
    if (idx < NST) {
      int r = idx / TWX, c = idx - r * TWX;
      int r1 = (r < TWY - 1) ? r + 1 : r;
      int c1 = (c < TWX - 1) ? c + 1 : c;
      float v00 = Fm[r * TWX + c],  v01 = Fm[r * TWX + c1];
      float v10 = Fm[r1 * TWX + c], v11 = Fm[r1 * TWX + c1];
      Qd[idx] = make_float4(v00, v01 - v00, v10 - v00, (v11 - v10) - (v01 - v00));
    }
  }
  __syncthreads();
  const int gi = bx0 + HALO + tx;
  const int gj = by0 + HALO + ty;
  const float SC = (float)(512.0 / 511.0);
  const float axl = fmaf((float)gi, SC, -0.5f) - (float)bx0;
  const float ayl = fmaf((float)gj, SC, -0.5f) - (float)by0;
  float wn[8];
  #pragma unroll
  for (int n = 0; n < 8; ++n) wn[n] = tbl[96 + n];
  float SY = 0.f, CX = 0.f;
  for (int q = 0; q < 24; ++q) {
    const float csx = tbl[48 + q];
    const float ssy = tbl[72 + q];
    float e2 = 0.f;
    #pragma unroll
    for (int n = 0; n < 8; ++n) {
      const float tn = 0.375f * (float)(n + 1);
      float px = fmaf(-csx, tn, axl);
      float py = fmaf(-ssy, tn, ayl);
      int ix = (int)px, iy = (int)py;
      float fx = FRACTF(px), fy = FRACTF(py);
      float4 v = Qd[iy * TWX + ix];
      float s = fmaf(fx * fy, v.w, fmaf(fy, v.z, fmaf(fx, v.y, v.x)));
      e2 = fmaf(wn[n], s, e2);
    }
    float e = EXP2F(e2);
    SY = fmaf(e, tbl[24 + q], SY);
    CX = fmaf(e, tbl[q], CX);
  }
  const int* ti = (const int*)tbl;
  const int cbase = (ty + 1) * TWX + tx + 1;
  float a0 = 0.f, a1 = 0.f, a2 = 0.f, a3 = 0.f;
  if (ti[107] == 0) {
    #pragma unroll
    for (int t2 = 0; t2 < 8; ++t2) {
      a0 = fmaf(Sm[cbase + ti[140 + t2]], tbl[108 + t2], a0);
      a1 = fmaf(Sm[cbase + ti[148 + t2]], tbl[116 + t2], a1);
      a2 = fmaf(Sm[cbase + ti[156 + t2]], tbl[124 + t2], a2);
      a3 = fmaf(Sm[cbase + ti[164 + t2]], tbl[132 + t2], a3);
    }
  } else {
    for (int kj = 0; kj < 7; ++kj)
      for (int ki = 0; ki < 7; ++ki) {
        float s = Sm[(ty + 1 + kj) * TWX + (tx + 1 + ki)];
        int k = kj * 7 + ki;
        a0 = fmaf(s, Wb[k], a0); a1 = fmaf(s, Wb[49 + k], a1);
        a2 = fmaf(s, Wb[98 + k], a2); a3 = fmaf(s, Wb[147 + k], a3);
      }
  }
  const float TP  = 6.283185307179586f;
  const float PIF = 3.14159265358979323846f;
  const float HP  = 1.57079632679489661923f;
  float hat = atan2f(SY, CX);
  float r1 = hat + TP;
  r1 = (r1 >= TP) ? (r1 - TP) : r1;
  float theta = (r1 >= PIF) ? (r1 - PIF) : r1;
  const float irt2  = tbl[104];
  const float gamma = tbl[105];
  const float gainc = tbl[106];
  float dist[4];
  #pragma unroll
  for (int o = 0; o < 4; ++o) {
    float d = theta - cen[o] + HP;
    d -= (d >= PIF) ? PIF : 0.f;
    d += (d < 0.f) ? PIF : 0.f;
    dist[o] = fabsf(d - HP);
  }
  float mn = fminf(fminf(dist[0], dist[1]), fminf(dist[2], dist[3]));
  float m2 = mn * irt2;
  float eo[4], Z = 0.f;
  #pragma unroll
  for (int o = 0; o < 4; ++o) { eo[o] = EXP2F(fmaf(-irt2, dist[o], m2)); Z += eo[o]; }
  float invZ = 1.0f / Z;
  float sh[4], Zs = 0.f;
  #pragma unroll
  for (int o = 0; o < 4; ++o) {
    sh[o] = EXP2F(gamma * LOG2F(fmaf(eo[o], invZ, 1e-12f)));
    Zs += sh[o];
  }
  float wsi = 1.0f / (Zs + 1e-8f);
  float ov = (a0 * sh[0] + a1 * sh[1] + a2 * sh[2] + a3 * sh[3]) * wsi;
  out[((size_t)b * 512 + gj) * 512 + gi] = gainc * ov;
}

extern "C" void kernel_launch(void* const* d_in, const int* in_sizes, int n_in,
                              void* d_out, int out_size, void* d_ws, size_t ws_size,
                              hipStream_t stream) {
  const float* x    = (const float*)d_in[0];
  const float* gain = (const float*)d_in[1];
  const float* lrt  = (const float*)d_in[2];
  const float* rlg  = (const float*)d_in[3];
  const float* Wb   = (const float*)d_in[4];
  const float* cen  = (const float*)d_in[5];
  float* tbl = (float*)d_ws;

  gp_setup<<<1, 64, 0, stream>>>(gain, lrt, rlg, Wb, tbl);

  size_t need = 4096 + (size_t)8 * QIH * QIW * sizeof(float4);
  if (ws_size >= need) {
    float4* qimg = (float4*)((char*)d_ws + 4096);
    gp_quad2<<<dim3((QIH + 63) / 64, QIH / 4, 8), dim3(256), 0, stream>>>(x, qimg);
    gp_main3<<<dim3(8192), dim3(256), 0, stream>>>(x, qimg, Wb, cen, tbl, (float*)d_out);
  } else {
    gp_main_fb<<<dim3(8, 128, 8), dim3(64, 4), 0, stream>>>(x, Wb, cen, tbl, (float*)d_out);
  }
}

// Round 5
// 171.496 us; speedup vs baseline: 1.0174x; 1.0174x over previous
//
#include <hip/hip_runtime.h>
#include <math.h>

#define HALO 4
#define TWX 72
#define QIW 528
#define QIH 520

#if __has_builtin(__builtin_amdgcn_fractf)
#define FRACTF(x) __builtin_amdgcn_fractf(x)
#else
#define FRACTF(x) ((x) - floorf(x))
#endif
#if __has_builtin(__builtin_amdgcn_exp2f)
#define EXP2F(x) __builtin_amdgcn_exp2f(x)
#else
#define EXP2F(x) exp2f(x)
#endif
#if __has_builtin(__builtin_amdgcn_logf)
#define LOG2F(x) __builtin_amdgcn_logf(x)
#else
#define LOG2F(x) log2f(x)
#endif

// tbl layout (floats):
// [0..23] cos_q  [24..47] sin_q  [48..71] cos_q*SC  [72..95] sin_q*SC
// [96..103] wn_norm*log2e  [104] irt*log2e  [105] gamma  [106] gain
// [107] dense flag (int)  [108..139] sparse tap w  [140..171] sparse tap off (int)
// [172] fastconv ok flag (int)  [180..183] per-bank equal weight
__global__ __launch_bounds__(64) void gp_setup(const float* __restrict__ gain,
                                               const float* __restrict__ lrt,
                                               const float* __restrict__ rlg,
                                               const float* __restrict__ Wb,
                                               float* __restrict__ tbl) {
  int t = threadIdx.x;
  __shared__ float wtmp[8];
  if (t < 8) {
    float tn = (float)(t + 1) * 0.375f;
    wtmp[t] = expf(-0.5f * tn * tn);
  }
  if (t < 24) {
    float th = (6.283185307179586f * (float)t) / 24.0f;
    float c = cosf(th), s = sinf(th);
    const float sc = (float)(512.0 / 511.0);
    tbl[t] = c; tbl[24 + t] = s; tbl[48 + t] = c * sc; tbl[72 + t] = s * sc;
  }
  __syncthreads();
  if (t == 0) {
    const float L2E = 1.44269504088896340736f;
    float sum = 0.f;
    for (int n = 0; n < 8; ++n) sum += wtmp[n];
    for (int n = 0; n < 8; ++n) tbl[96 + n] = (wtmp[n] / sum) * L2E;
    float rt = expf(lrt[0]);
    rt = fminf(fmaxf(rt, 0.001f), 2.0f);
    float sg = 1.0f / (1.0f + expf(-rlg[0]));
    float rho = sg * 0.95f + 0.05f;
    tbl[104] = (1.0f / rt) * L2E;
    tbl[105] = 1.0f / (rho + 1e-8f);
    tbl[106] = fmaxf(gain[0], 0.001f);

    int* ti = (int*)tbl;
    int dense = 0;
    for (int o = 0; o < 4; ++o) {
      int cnt = 0;
      for (int k = 0; k < 49; ++k) {
        float w = Wb[o * 49 + k];
        if (w != 0.0f) {
          if (cnt < 8) {
            int kj = k / 7, ki = k - kj * 7;
            tbl[108 + o * 8 + cnt] = w;
            ti[140 + o * 8 + cnt] = kj * TWX + ki;
          }
          cnt++;
        }
      }
      if (cnt > 8) dense = 1;
      for (int c2 = cnt; c2 < 8; ++c2) { tbl[108 + o * 8 + c2] = 0.f; ti[140 + o * 8 + c2] = 0; }
    }
    ti[107] = dense;

    const int K0[7] = {14,15,23,24,25,33,34};
    const int K1[7] = {2,9,17,24,31,39,46};
    const int K2[7] = {4,11,17,24,31,37,44};
    const int K3[7] = {19,20,23,24,25,28,29};
    const int* KK[4] = {K0,K1,K2,K3};
    int ok = 1;
    for (int o = 0; o < 4; ++o) {
      float w0v = Wb[o * 49 + KK[o][0]];
      if (w0v == 0.f) ok = 0;
      unsigned long long mask = 0;
      for (int t2 = 0; t2 < 7; ++t2) mask |= 1ull << KK[o][t2];
      for (int k = 0; k < 49; ++k) {
        float w = Wb[o * 49 + k];
        int nz = (w != 0.f);
        int want = (int)((mask >> k) & 1ull);
        if (nz != want) ok = 0;
        if (nz && w != w0v) ok = 0;
      }
      tbl[180 + o] = w0v;
    }
    ti[172] = ok;
  }
}

__device__ inline float fmv(const float* __restrict__ x0p, const float* __restrict__ x1p,
                            int Y, int X) {
  int cY = min(max(Y, 0), 511);
  int cX = min(max(X, 0), 511);
  size_t o = (size_t)cY * 512 + cX;
  float a = x0p[o], b = x1p[o];
  float f = sqrtf(a * a + b * b);
  return ((unsigned)X < 512u && (unsigned)Y < 512u) ? f : 0.f;
}

// Prepass: 1 thread = 1 pre-differenced quad (no LDS, clamped loads).
__global__ __launch_bounds__(256) void gp_quad3(const float* __restrict__ x,
                                                float4* __restrict__ qimg) {
  int idx = blockIdx.x * 256 + threadIdx.x;
  if (idx >= QIH * QIW) return;
  int b = blockIdx.y;
  int yy = idx / QIW, xx = idx - yy * QIW;
  int X = xx - 4, Y = yy - 4;
  const float* __restrict__ x0p = x + (size_t)b * 2 * 512 * 512;
  const float* __restrict__ x1p = x0p + 512 * 512;
  float f00 = fmv(x0p, x1p, Y, X);
  float f01 = fmv(x0p, x1p, Y, X + 1);
  float f10 = fmv(x0p, x1p, Y + 1, X);
  float f11 = fmv(x0p, x1p, Y + 1, X + 1);
  qimg[(size_t)b * (QIH * QIW) + idx] =
      make_float4(f00, f01 - f00, f10 - f00, (f11 - f10) - (f01 - f00));
}

__device__ inline float finish(float SY, float CX, float a0, float a1, float a2,
                               float a3, const float* __restrict__ cen,
                               float irt2, float gamma, float gainc) {
  const float TP  = 6.283185307179586f;
  const float PIF = 3.14159265358979323846f;
  const float HP  = 1.57079632679489661923f;
  float hat = atan2f(SY, CX);
  float r1 = hat + TP;
  r1 = (r1 >= TP) ? (r1 - TP) : r1;
  float theta = (r1 >= PIF) ? (r1 - PIF) : r1;
  float dist[4];
  #pragma unroll
  for (int o = 0; o < 4; ++o) {
    float d = theta - cen[o] + HP;
    d -= (d >= PIF) ? PIF : 0.f;
    d += (d < 0.f) ? PIF : 0.f;
    dist[o] = fabsf(d - HP);
  }
  float mn = fminf(fminf(dist[0], dist[1]), fminf(dist[2], dist[3]));
  float m2 = mn * irt2;
  float eo[4], Z = 0.f;
  #pragma unroll
  for (int o = 0; o < 4; ++o) { eo[o] = EXP2F(fmaf(-irt2, dist[o], m2)); Z += eo[o]; }
  float invZ = 1.0f / Z;
  float sh[4], Zs = 0.f;
  #pragma unroll
  for (int o = 0; o < 4; ++o) {
    sh[o] = EXP2F(gamma * LOG2F(fmaf(eo[o], invZ, 1e-12f)));
    Zs += sh[o];
  }
  float wsi = 1.0f / (Zs + 1e-8f);
  return gainc * ((a0 * sh[0] + a1 * sh[1] + a2 * sh[2] + a3 * sh[3]) * wsi);
}

// Main: 2 pixels/thread (rows ty, ty+4 of a 64x8 tile), shared x-side math.
// Pixel A samples LDS window; pixel B samples quad image via VMEM (SGPR base
// + 32-bit offset). 17.7KB LDS + <=64 VGPR -> 32 waves/CU.
__global__ __launch_bounds__(256, 8) void gp_main5(const float* __restrict__ x,
                                                   const float4* __restrict__ qimg,
                                                   const float* __restrict__ Wb,
                                                   const float* __restrict__ cen,
                                                   const float* __restrict__ tbl,
                                                   float* __restrict__ out) {
  __shared__ float4 Qd[12 * 72];   // pixel-A window rows 0..11
  __shared__ float  Sm[14 * 70];   // conv window, halo 3

  const int tid = threadIdx.x;
  const int tx = tid & 63, ty = tid >> 6;
  int wg = blockIdx.x;
  int swz = (wg & 7) * 512 + (wg >> 3);   // XCD k -> batch k
  int bx = swz & 7;
  int by = (swz >> 3) & 63;
  int b  = swz >> 9;

  const float* __restrict__ x0p = x + (size_t)b * 2 * 512 * 512;
  const float* __restrict__ x1p = x0p + 512 * 512;
  // qb: window (row r, col c) of this tile = qimg row by*8+r, col bx*64+c
  const float4* __restrict__ qb = qimg + (size_t)b * (QIH * QIW) + (by * 8) * QIW + bx * 64;

  #pragma unroll
  for (int it = 0; it < 4; ++it) {
    int idx = tid + it * 256;
    if (idx < 864) {
      int r = idx / 72, c = idx - r * 72;
      Qd[idx] = qb[r * QIW + c];
    }
  }
  const int sy0 = by * 8 - 3, sx0 = bx * 64 - 3;
  #pragma unroll
  for (int it = 0; it < 4; ++it) {
    int idx = tid + it * 256;
    if (idx < 980) {
      int r = idx / 70, c = idx - r * 70;
      int gy = sy0 + r, gx = sx0 + c;
      float a = 0.f, bv = 0.f;
      if ((unsigned)gx < 512u && (unsigned)gy < 512u) {
        size_t o = (size_t)gy * 512 + gx;
        a = x0p[o]; bv = x1p[o];
      }
      Sm[idx] = a + bv;
    }
  }
  __syncthreads();

  const int gi  = bx * 64 + tx;
  const int gjA = by * 8 + ty;        // pixel A row; pixel B = gjA + 4
  const float SC = (float)(512.0 / 511.0);
  const float bx0 = (float)(bx * 64 - HALO), by0 = (float)(by * 8 - HALO);
  const float axl  = fmaf((float)gi, SC, -0.5f) - bx0;        // window coords, >0
  const float aylA = fmaf((float)gjA, SC, -0.5f) - by0;
  const float aylB = fmaf((float)(gjA + 4), SC, -0.5f) - by0;

  float wn[8];
  #pragma unroll
  for (int n = 0; n < 8; ++n) wn[n] = tbl[96 + n];   // uniform -> SGPR

  float SYA = 0.f, CXA = 0.f, SYB = 0.f, CXB = 0.f;
  for (int q = 0; q < 24; ++q) {
    const float cs = tbl[48 + q];
    const float sn = tbl[72 + q];
    float eA = 0.f, eB = 0.f;
    #pragma unroll
    for (int n = 0; n < 8; ++n) {
      const float tn = 0.375f * (float)(n + 1);
      float px  = fmaf(-cs, tn, axl);          // shared between A and B
      int   ix  = (int)px;
      float fx  = FRACTF(px);
      float pyA = fmaf(-sn, tn, aylA);
      int   iyA = (int)pyA;
      float fyA = FRACTF(pyA);
      float pyB = fmaf(-sn, tn, aylB);
      int   iyB = (int)pyB;
      float fyB = FRACTF(pyB);
      float4 vA = Qd[iyA * 72 + ix];           // LDS pipe
      float4 vB = qb[iyB * QIW + ix];          // VMEM pipe (L1/L2)
      float sA = fmaf(fyA, fmaf(fx, vA.w, vA.z), fmaf(fx, vA.y, vA.x));
      float sB = fmaf(fyB, fmaf(fx, vB.w, vB.z), fmaf(fx, vB.y, vB.x));
      eA = fmaf(wn[n], sA, eA);
      eB = fmaf(wn[n], sB, eB);
    }
    float ea = EXP2F(eA), eb = EXP2F(eB);
    SYA = fmaf(ea, tbl[24 + q], SYA); CXA = fmaf(ea, tbl[q], CXA);
    SYB = fmaf(eb, tbl[24 + q], SYB); CXB = fmaf(eb, tbl[q], CXB);
  }

  // Conv (Sm stride 70, halo 3). Fast path: verified line masks, equal weights.
  const int* ti = (const int*)tbl;
  const int cA = (ty + 3) * 70 + tx + 3;
  const int cB = cA + 4 * 70;
  float a0A, a1A, a2A, a3A, a0B, a1B, a2B, a3B;
  if (ti[172]) {
    {
      float sC = Sm[cA];
      float H3 = (Sm[cA - 1] + sC) + Sm[cA + 1];
      float V3 = (Sm[cA - 70] + sC) + Sm[cA + 70];
      a0A = tbl[180] * (H3 + ((Sm[cA - 73] + Sm[cA - 72]) + (Sm[cA + 72] + Sm[cA + 73])));
      a1A = tbl[181] * (V3 + ((Sm[cA - 211] + Sm[cA - 141]) + (Sm[cA + 141] + Sm[cA + 211])));
      a2A = tbl[182] * (V3 + ((Sm[cA - 209] + Sm[cA - 139]) + (Sm[cA + 139] + Sm[cA + 209])));
      a3A = tbl[183] * (H3 + ((Sm[cA - 68] + Sm[cA - 67]) + (Sm[cA + 67] + Sm[cA + 68])));
    }
    {
      float sC = Sm[cB];
      float H3 = (Sm[cB - 1] + sC) + Sm[cB + 1];
      float V3 = (Sm[cB - 70] + sC) + Sm[cB + 70];
      a0B = tbl[180] * (H3 + ((Sm[cB - 73] + Sm[cB - 72]) + (Sm[cB + 72] + Sm[cB + 73])));
      a1B = tbl[181] * (V3 + ((Sm[cB - 211] + Sm[cB - 141]) + (Sm[cB + 141] + Sm[cB + 211])));
      a2B = tbl[182] * (V3 + ((Sm[cB - 209] + Sm[cB - 139]) + (Sm[cB + 139] + Sm[cB + 209])));
      a3B = tbl[183] * (H3 + ((Sm[cB - 68] + Sm[cB - 67]) + (Sm[cB + 67] + Sm[cB + 68])));
    }
  } else {
    a0A = a1A = a2A = a3A = 0.f;
    a0B = a1B = a2B = a3B = 0.f;
    for (int kj = 0; kj < 7; ++kj)
      for (int ki = 0; ki < 7; ++ki) {
        int k = kj * 7 + ki;
        float sA = Sm[(ty + kj) * 70 + (tx + ki)];
        float sB = Sm[(ty + 4 + kj) * 70 + (tx + ki)];
        a0A = fmaf(sA, Wb[k], a0A);       a0B = fmaf(sB, Wb[k], a0B);
        a1A = fmaf(sA, Wb[49 + k], a1A);  a1B = fmaf(sB, Wb[49 + k], a1B);
        a2A = fmaf(sA, Wb[98 + k], a2A);  a2B = fmaf(sB, Wb[98 + k], a2B);
        a3A = fmaf(sA, Wb[147 + k], a3A); a3B = fmaf(sB, Wb[147 + k], a3B);
      }
  }

  const float irt2  = tbl[104];
  const float gamma = tbl[105];
  const float gainc = tbl[106];

  float outA = finish(SYA, CXA, a0A, a1A, a2A, a3A, cen, irt2, gamma, gainc);
  float outB = finish(SYB, CXB, a0B, a1B, a2B, a3B, cen, irt2, gamma, gainc);

  size_t ob = ((size_t)b * 512 + gjA) * 512 + gi;
  out[ob] = outA;
  out[ob + 4 * 512] = outB;
}

// Fallback (ws too small): Round-2 kernel verbatim (proven 146us path).
__global__ __launch_bounds__(256) void gp_main_fb(const float* __restrict__ x,
                                                  const float* __restrict__ Wb,
                                                  const float* __restrict__ cen,
                                                  const float* __restrict__ tbl,
                                                  float* __restrict__ out) {
  __shared__ float  Fm[12 * 72];
  __shared__ float  Sm[12 * 72];
  __shared__ float4 Qd[12 * 72];
  const int tx = threadIdx.x;
  const int ty = threadIdx.y;
  const int tid = ty * 64 + tx;
  const int bx0 = blockIdx.x * 64 - HALO;
  const int by0 = blockIdx.y * 4 - HALO;
  const int b = blockIdx.z;
  const float* __restrict__ x0p = x + (size_t)b * 2 * 512 * 512;
  const float* __restrict__ x1p = x0p + 512 * 512;
  #pragma unroll
  for (int it = 0; it < 4; ++it) {
    int idx = tid + it * 256;
    if (idx < 864) {
      int r = idx / TWX, c = idx - r * TWX;
      int gy = by0 + r, gx = bx0 + c;
      float a = 0.f, bv = 0.f;
      if ((unsigned)gx < 512u && (unsigned)gy < 512u) {
        size_t o = (size_t)gy * 512 + gx;
        a = x0p[o]; bv = x1p[o];
      }
      Fm[idx] = sqrtf(a * a + bv * bv);
      Sm[idx] = a + bv;
    }
  }
  __syncthreads();
  #pragma unroll
  for (int it = 0; it < 4; ++it) {
    int idx = tid + it * 256;
    if (idx < 864) {
      int r = idx / TWX, c = idx - r * TWX;
      int r1 = (r < 11) ? r + 1 : r;
      int c1 = (c < TWX - 1) ? c + 1 : c;
      float v00 = Fm[r * TWX + c],  v01 = Fm[r * TWX + c1];
      float v10 = Fm[r1 * TWX + c], v11 = Fm[r1 * TWX + c1];
      Qd[idx] = make_float4(v00, v01 - v00, v10 - v00, (v11 - v10) - (v01 - v00));
    }
  }
  __syncthreads();
  const int gi = bx0 + HALO + tx;
  const int gj = by0 + HALO + ty;
  const float SC = (float)(512.0 / 511.0);
  const float axl = fmaf((float)gi, SC, -0.5f) - (float)bx0;
  const float ayl = fmaf((float)gj, SC, -0.5f) - (float)by0;
  float wn[8];
  #pragma unroll
  for (int n = 0; n < 8; ++n) wn[n] = tbl[96 + n];
  float SY = 0.f, CX = 0.f;
  for (int q = 0; q < 24; ++q) {
    const float csx = tbl[48 + q];
    const float ssy = tbl[72 + q];
    float e2 = 0.f;
    #pragma unroll
    for (int n = 0; n < 8; ++n) {
      const float tn = 0.375f * (float)(n + 1);
      float px = fmaf(-csx, tn, axl);
      float py = fmaf(-ssy, tn, ayl);
      int ix = (int)px, iy = (int)py;
      float fx = FRACTF(px), fy = FRACTF(py);
      float4 v = Qd[iy * TWX + ix];
      float s = fmaf(fx * fy, v.w, fmaf(fy, v.z, fmaf(fx, v.y, v.x)));
      e2 = fmaf(wn[n], s, e2);
    }
    float e = EXP2F(e2);
    SY = fmaf(e, tbl[24 + q], SY);
    CX = fmaf(e, tbl[q], CX);
  }
  const int* ti = (const int*)tbl;
  const int cbase = (ty + 1) * TWX + tx + 1;
  float a0 = 0.f, a1 = 0.f, a2 = 0.f, a3 = 0.f;
  if (ti[107] == 0) {
    #pragma unroll
    for (int t2 = 0; t2 < 8; ++t2) {
      a0 = fmaf(Sm[cbase + ti[140 + t2]], tbl[108 + t2], a0);
      a1 = fmaf(Sm[cbase + ti[148 + t2]], tbl[116 + t2], a1);
      a2 = fmaf(Sm[cbase + ti[156 + t2]], tbl[124 + t2], a2);
      a3 = fmaf(Sm[cbase + ti[164 + t2]], tbl[132 + t2], a3);
    }
  } else {
    for (int kj = 0; kj < 7; ++kj)
      for (int ki = 0; ki < 7; ++ki) {
        float s = Sm[(ty + 1 + kj) * TWX + (tx + 1 + ki)];
        int k = kj * 7 + ki;
        a0 = fmaf(s, Wb[k], a0); a1 = fmaf(s, Wb[49 + k], a1);
        a2 = fmaf(s, Wb[98 + k], a2); a3 = fmaf(s, Wb[147 + k], a3);
      }
  }
  const float irt2  = tbl[104];
  const float gamma = tbl[105];
  const float gainc = tbl[106];
  float ov = finish(SY, CX, a0, a1, a2, a3, cen, irt2, gamma, gainc);
  out[((size_t)b * 512 + gj) * 512 + gi] = ov;
}

extern "C" void kernel_launch(void* const* d_in, const int* in_sizes, int n_in,
                              void* d_out, int out_size, void* d_ws, size_t ws_size,
                              hipStream_t stream) {
  const float* x    = (const float*)d_in[0];
  const float* gain = (const float*)d_in[1];
  const float* lrt  = (const float*)d_in[2];
  const float* rlg  = (const float*)d_in[3];
  const float* Wb   = (const float*)d_in[4];
  const float* cen  = (const float*)d_in[5];
  float* tbl = (float*)d_ws;

  gp_setup<<<1, 64, 0, stream>>>(gain, lrt, rlg, Wb, tbl);

  size_t need = 4096 + (size_t)8 * QIH * QIW * sizeof(float4);
  if (ws_size >= need) {
    float4* qimg = (float4*)((char*)d_ws + 4096);
    gp_quad3<<<dim3((QIH * QIW + 255) / 256, 8), 256, 0, stream>>>(x, qimg);
    gp_main5<<<dim3(4096), dim3(256), 0, stream>>>(x, qimg, Wb, cen, tbl, (float*)d_out);
  } else {
    gp_main_fb<<<dim3(8, 128, 8), dim3(64, 4), 0, stream>>>(x, Wb, cen, tbl, (float*)d_out);
  }
}

// Round 6
// 159.701 us; speedup vs baseline: 1.0925x; 1.0739x over previous
//
#include <hip/hip_runtime.h>
#include <math.h>

#define HALO 4
#define TWX 72
#define QIW 528
#define QIH 520

#if __has_builtin(__builtin_amdgcn_fractf)
#define FRACTF(x) __builtin_amdgcn_fractf(x)
#else
#define FRACTF(x) ((x) - floorf(x))
#endif
#if __has_builtin(__builtin_amdgcn_exp2f)
#define EXP2F(x) __builtin_amdgcn_exp2f(x)
#else
#define EXP2F(x) exp2f(x)
#endif
#if __has_builtin(__builtin_amdgcn_logf)
#define LOG2F(x) __builtin_amdgcn_logf(x)
#else
#define LOG2F(x) log2f(x)
#endif

// tbl layout (floats):
// [0..23] cos_q  [24..47] sin_q  [48..71] cos_q*SC  [72..95] sin_q*SC
// [96..103] wn_norm*log2e  [104] irt*log2e  [105] gamma  [106] gain
// [107] dense flag (int)  [108..139] sparse tap w  [140..171] sparse tap off (int)
// [172] fastconv ok flag (int)  [180..183] per-bank equal weight
__global__ __launch_bounds__(64) void gp_setup(const float* __restrict__ gain,
                                               const float* __restrict__ lrt,
                                               const float* __restrict__ rlg,
                                               const float* __restrict__ Wb,
                                               float* __restrict__ tbl) {
  int t = threadIdx.x;
  __shared__ float wtmp[8];
  if (t < 8) {
    float tn = (float)(t + 1) * 0.375f;
    wtmp[t] = expf(-0.5f * tn * tn);
  }
  if (t < 24) {
    float th = (6.283185307179586f * (float)t) / 24.0f;
    float c = cosf(th), s = sinf(th);
    const float sc = (float)(512.0 / 511.0);
    tbl[t] = c; tbl[24 + t] = s; tbl[48 + t] = c * sc; tbl[72 + t] = s * sc;
  }
  __syncthreads();
  if (t == 0) {
    const float L2E = 1.44269504088896340736f;
    float sum = 0.f;
    for (int n = 0; n < 8; ++n) sum += wtmp[n];
    for (int n = 0; n < 8; ++n) tbl[96 + n] = (wtmp[n] / sum) * L2E;
    float rt = expf(lrt[0]);
    rt = fminf(fmaxf(rt, 0.001f), 2.0f);
    float sg = 1.0f / (1.0f + expf(-rlg[0]));
    float rho = sg * 0.95f + 0.05f;
    tbl[104] = (1.0f / rt) * L2E;
    tbl[105] = 1.0f / (rho + 1e-8f);
    tbl[106] = fmaxf(gain[0], 0.001f);

    int* ti = (int*)tbl;
    int dense = 0;
    for (int o = 0; o < 4; ++o) {
      int cnt = 0;
      for (int k = 0; k < 49; ++k) {
        float w = Wb[o * 49 + k];
        if (w != 0.0f) {
          if (cnt < 8) {
            int kj = k / 7, ki = k - kj * 7;
            tbl[108 + o * 8 + cnt] = w;
            ti[140 + o * 8 + cnt] = kj * TWX + ki;
          }
          cnt++;
        }
      }
      if (cnt > 8) dense = 1;
      for (int c2 = cnt; c2 < 8; ++c2) { tbl[108 + o * 8 + c2] = 0.f; ti[140 + o * 8 + c2] = 0; }
    }
    ti[107] = dense;

    const int K0[7] = {14,15,23,24,25,33,34};
    const int K1[7] = {2,9,17,24,31,39,46};
    const int K2[7] = {4,11,17,24,31,37,44};
    const int K3[7] = {19,20,23,24,25,28,29};
    const int* KK[4] = {K0,K1,K2,K3};
    int ok = 1;
    for (int o = 0; o < 4; ++o) {
      float w0v = Wb[o * 49 + KK[o][0]];
      if (w0v == 0.f) ok = 0;
      unsigned long long mask = 0;
      for (int t2 = 0; t2 < 7; ++t2) mask |= 1ull << KK[o][t2];
      for (int k = 0; k < 49; ++k) {
        float w = Wb[o * 49 + k];
        int nz = (w != 0.f);
        int want = (int)((mask >> k) & 1ull);
        if (nz != want) ok = 0;
        if (nz && w != w0v) ok = 0;
      }
      tbl[180 + o] = w0v;
    }
    ti[172] = ok;
  }
}

__device__ inline float fmv(const float* __restrict__ x0p, const float* __restrict__ x1p,
                            int Y, int X) {
  int cY = min(max(Y, 0), 511);
  int cX = min(max(X, 0), 511);
  size_t o = (size_t)cY * 512 + cX;
  float a = x0p[o], b = x1p[o];
  float f = sqrtf(a * a + b * b);
  return ((unsigned)X < 512u && (unsigned)Y < 512u) ? f : 0.f;
}

// Prepass: 1 thread = 1 pre-differenced quad.
__global__ __launch_bounds__(256) void gp_quad3(const float* __restrict__ x,
                                                float4* __restrict__ qimg) {
  int idx = blockIdx.x * 256 + threadIdx.x;
  if (idx >= QIH * QIW) return;
  int b = blockIdx.y;
  int yy = idx / QIW, xx = idx - yy * QIW;
  int X = xx - 4, Y = yy - 4;
  const float* __restrict__ x0p = x + (size_t)b * 2 * 512 * 512;
  const float* __restrict__ x1p = x0p + 512 * 512;
  float f00 = fmv(x0p, x1p, Y, X);
  float f01 = fmv(x0p, x1p, Y, X + 1);
  float f10 = fmv(x0p, x1p, Y + 1, X);
  float f11 = fmv(x0p, x1p, Y + 1, X + 1);
  qimg[(size_t)b * (QIH * QIW) + idx] =
      make_float4(f00, f01 - f00, f10 - f00, (f11 - f10) - (f01 - f00));
}

__device__ inline float finish(float SY, float CX, float a0, float a1, float a2,
                               float a3, const float* __restrict__ cen,
                               float irt2, float gamma, float gainc) {
  const float TP  = 6.283185307179586f;
  const float PIF = 3.14159265358979323846f;
  const float HP  = 1.57079632679489661923f;
  float hat = atan2f(SY, CX);
  float r1 = hat + TP;
  r1 = (r1 >= TP) ? (r1 - TP) : r1;
  float theta = (r1 >= PIF) ? (r1 - PIF) : r1;
  float dist[4];
  #pragma unroll
  for (int o = 0; o < 4; ++o) {
    float d = theta - cen[o] + HP;
    d -= (d >= PIF) ? PIF : 0.f;
    d += (d < 0.f) ? PIF : 0.f;
    dist[o] = fabsf(d - HP);
  }
  float mn = fminf(fminf(dist[0], dist[1]), fminf(dist[2], dist[3]));
  float m2 = mn * irt2;
  float eo[4], Z = 0.f;
  #pragma unroll
  for (int o = 0; o < 4; ++o) { eo[o] = EXP2F(fmaf(-irt2, dist[o], m2)); Z += eo[o]; }
  float invZ = 1.0f / Z;
  float sh[4], Zs = 0.f;
  #pragma unroll
  for (int o = 0; o < 4; ++o) {
    sh[o] = EXP2F(gamma * LOG2F(fmaf(eo[o], invZ, 1e-12f)));
    Zs += sh[o];
  }
  float wsi = 1.0f / (Zs + 1e-8f);
  return gainc * ((a0 * sh[0] + a1 * sh[1] + a2 * sh[2] + a3 * sh[3]) * wsi);
}

// Per-q sample machinery: named registers, fully unrolled, loads batched
// so 8 ds_read_b128 + 8 global_load_dwordx4 are simultaneously in flight.
#define TN0 0.375f
#define TN1 0.75f
#define TN2 1.125f
#define TN3 1.5f
#define TN4 1.875f
#define TN5 2.25f
#define TN6 2.625f
#define TN7 3.0f

#define COORD(n) \
  float px##n  = fmaf(-cs, TN##n, axl); \
  int   ix##n  = (int)px##n; \
  float fx##n  = FRACTF(px##n); \
  float pyA##n = fmaf(-sn, TN##n, aylA); \
  float pyB##n = fmaf(-sn, TN##n, aylB); \
  int   iyA##n = (int)pyA##n; \
  int   iyB##n = (int)pyB##n; \
  float fyA##n = FRACTF(pyA##n); \
  float fyB##n = FRACTF(pyB##n); \
  int      offA##n = iyA##n * 72 + ix##n; \
  unsigned offB##n = (unsigned)(iyB##n * QIW + ix##n);

#define LOADA(n) float4 A##n = Qd[offA##n];
#define LOADB(n) float4 B##n = qb[offB##n];

#define CONSA(n) { \
  float sA = fmaf(fyA##n, fmaf(fx##n, A##n.w, A##n.z), fmaf(fx##n, A##n.y, A##n.x)); \
  eA = fmaf(wn##n, sA, eA); }
#define CONSB(n) { \
  float sB = fmaf(fyB##n, fmaf(fx##n, B##n.w, B##n.z), fmaf(fx##n, B##n.y, B##n.x)); \
  eB = fmaf(wn##n, sB, eB); }

// Main: 2 pixels/thread (rows ty, ty+4 of a 64x8 tile). Pixel A from LDS,
// pixel B from quad image (SGPR base + 32-bit voffset). launch_bounds(256,4)
// gives a 128-VGPR budget so all 16 loads per q stay in flight.
__global__ __launch_bounds__(256, 4) void gp_main6(const float* __restrict__ x,
                                                   const float4* __restrict__ qimg,
                                                   const float* __restrict__ Wb,
                                                   const float* __restrict__ cen,
                                                   const float* __restrict__ tbl,
                                                   float* __restrict__ out) {
  __shared__ float4 Qd[12 * 72];
  __shared__ float  Sm[14 * 70];

  const int tid = threadIdx.x;
  const int tx = tid & 63, ty = tid >> 6;
  int wg = blockIdx.x;
  int swz = (wg & 7) * 512 + (wg >> 3);   // XCD k -> batch k
  int bx = swz & 7;
  int by = (swz >> 3) & 63;
  int b  = swz >> 9;

  const float* __restrict__ x0p = x + (size_t)b * 2 * 512 * 512;
  const float* __restrict__ x1p = x0p + 512 * 512;
  const float4* __restrict__ qb = qimg + (size_t)b * (QIH * QIW) + (by * 8) * QIW + bx * 64;

  #pragma unroll
  for (int it = 0; it < 4; ++it) {
    int idx = tid + it * 256;
    if (idx < 864) {
      int r = idx / 72, c = idx - r * 72;
      Qd[idx] = qb[(unsigned)(r * QIW + c)];
    }
  }
  const int sy0 = by * 8 - 3, sx0 = bx * 64 - 3;
  #pragma unroll
  for (int it = 0; it < 4; ++it) {
    int idx = tid + it * 256;
    if (idx < 980) {
      int r = idx / 70, c = idx - r * 70;
      int gy = sy0 + r, gx = sx0 + c;
      float a = 0.f, bv = 0.f;
      if ((unsigned)gx < 512u && (unsigned)gy < 512u) {
        size_t o = (size_t)gy * 512 + gx;
        a = x0p[o]; bv = x1p[o];
      }
      Sm[idx] = a + bv;
    }
  }
  __syncthreads();

  const int gi  = bx * 64 + tx;
  const int gjA = by * 8 + ty;
  const float SC = (float)(512.0 / 511.0);
  const float bx0 = (float)(bx * 64 - HALO), by0 = (float)(by * 8 - HALO);
  const float axl  = fmaf((float)gi, SC, -0.5f) - bx0;
  const float aylA = fmaf((float)gjA, SC, -0.5f) - by0;
  const float aylB = fmaf((float)(gjA + 4), SC, -0.5f) - by0;

  const float wn0 = tbl[96], wn1 = tbl[97], wn2 = tbl[98], wn3 = tbl[99];
  const float wn4 = tbl[100], wn5 = tbl[101], wn6 = tbl[102], wn7 = tbl[103];

  float SYA = 0.f, CXA = 0.f, SYB = 0.f, CXB = 0.f;
  for (int q = 0; q < 24; ++q) {
    const float cs = tbl[48 + q];
    const float sn = tbl[72 + q];
    float eA = 0.f, eB = 0.f;
    // 1) all coordinates / offsets (pure VALU, no memory)
    COORD(0) COORD(1) COORD(2) COORD(3) COORD(4) COORD(5) COORD(6) COORD(7)
    // 2) issue all 16 loads back-to-back (8 LDS + 8 VMEM in flight)
    LOADA(0) LOADA(1) LOADA(2) LOADA(3) LOADA(4) LOADA(5) LOADA(6) LOADA(7)
    LOADB(0) LOADB(1) LOADB(2) LOADB(3) LOADB(4) LOADB(5) LOADB(6) LOADB(7)
    // 3) consume (A first: lgkm drains in order while vmcnt keeps draining)
    CONSA(0) CONSA(1) CONSA(2) CONSA(3) CONSA(4) CONSA(5) CONSA(6) CONSA(7)
    CONSB(0) CONSB(1) CONSB(2) CONSB(3) CONSB(4) CONSB(5) CONSB(6) CONSB(7)
    float ea = EXP2F(eA), eb = EXP2F(eB);
    SYA = fmaf(ea, tbl[24 + q], SYA); CXA = fmaf(ea, tbl[q], CXA);
    SYB = fmaf(eb, tbl[24 + q], SYB); CXB = fmaf(eb, tbl[q], CXB);
  }

  const int* ti = (const int*)tbl;
  const int cA = (ty + 3) * 70 + tx + 3;
  const int cB = cA + 4 * 70;
  float a0A, a1A, a2A, a3A, a0B, a1B, a2B, a3B;
  if (ti[172]) {
    {
      float sC = Sm[cA];
      float H3 = (Sm[cA - 1] + sC) + Sm[cA + 1];
      float V3 = (Sm[cA - 70] + sC) + Sm[cA + 70];
      a0A = tbl[180] * (H3 + ((Sm[cA - 73] + Sm[cA - 72]) + (Sm[cA + 72] + Sm[cA + 73])));
      a1A = tbl[181] * (V3 + ((Sm[cA - 211] + Sm[cA - 141]) + (Sm[cA + 141] + Sm[cA + 211])));
      a2A = tbl[182] * (V3 + ((Sm[cA - 209] + Sm[cA - 139]) + (Sm[cA + 139] + Sm[cA + 209])));
      a3A = tbl[183] * (H3 + ((Sm[cA - 68] + Sm[cA - 67]) + (Sm[cA + 67] + Sm[cA + 68])));
    }
    {
      float sC = Sm[cB];
      float H3 = (Sm[cB - 1] + sC) + Sm[cB + 1];
      float V3 = (Sm[cB - 70] + sC) + Sm[cB + 70];
      a0B = tbl[180] * (H3 + ((Sm[cB - 73] + Sm[cB - 72]) + (Sm[cB + 72] + Sm[cB + 73])));
      a1B = tbl[181] * (V3 + ((Sm[cB - 211] + Sm[cB - 141]) + (Sm[cB + 141] + Sm[cB + 211])));
      a2B = tbl[182] * (V3 + ((Sm[cB - 209] + Sm[cB - 139]) + (Sm[cB + 139] + Sm[cB + 209])));
      a3B = tbl[183] * (H3 + ((Sm[cB - 68] + Sm[cB - 67]) + (Sm[cB + 67] + Sm[cB + 68])));
    }
  } else {
    a0A = a1A = a2A = a3A = 0.f;
    a0B = a1B = a2B = a3B = 0.f;
    for (int kj = 0; kj < 7; ++kj)
      for (int ki = 0; ki < 7; ++ki) {
        int k = kj * 7 + ki;
        float sA = Sm[(ty + kj) * 70 + (tx + ki)];
        float sB = Sm[(ty + 4 + kj) * 70 + (tx + ki)];
        a0A = fmaf(sA, Wb[k], a0A);       a0B = fmaf(sB, Wb[k], a0B);
        a1A = fmaf(sA, Wb[49 + k], a1A);  a1B = fmaf(sB, Wb[49 + k], a1B);
        a2A = fmaf(sA, Wb[98 + k], a2A);  a2B = fmaf(sB, Wb[98 + k], a2B);
        a3A = fmaf(sA, Wb[147 + k], a3A); a3B = fmaf(sB, Wb[147 + k], a3B);
      }
  }

  const float irt2  = tbl[104];
  const float gamma = tbl[105];
  const float gainc = tbl[106];

  float outA = finish(SYA, CXA, a0A, a1A, a2A, a3A, cen, irt2, gamma, gainc);
  float outB = finish(SYB, CXB, a0B, a1B, a2B, a3B, cen, irt2, gamma, gainc);

  size_t ob = ((size_t)b * 512 + gjA) * 512 + gi;
  out[ob] = outA;
  out[ob + 4 * 512] = outB;
}

// Fallback (ws too small): proven all-LDS single-kernel path.
__global__ __launch_bounds__(256) void gp_main_fb(const float* __restrict__ x,
                                                  const float* __restrict__ Wb,
                                                  const float* __restrict__ cen,
                                                  const float* __restrict__ tbl,
                                                  float* __restrict__ out) {
  __shared__ float  Fm[12 * 72];
  __shared__ float  Sm[12 * 72];
  __shared__ float4 Qd[12 * 72];
  const int tx = threadIdx.x;
  const int ty = threadIdx.y;
  const int tid = ty * 64 + tx;
  const int bx0 = blockIdx.x * 64 - HALO;
  const int by0 = blockIdx.y * 4 - HALO;
  const int b = blockIdx.z;
  const float* __restrict__ x0p = x + (size_t)b * 2 * 512 * 512;
  const float* __restrict__ x1p = x0p + 512 * 512;
  #pragma unroll
  for (int it = 0; it < 4; ++it) {
    int idx = tid + it * 256;
    if (idx < 864) {
      int r = idx / TWX, c = idx - r * TWX;
      int gy = by0 + r, gx = bx0 + c;
      float a = 0.f, bv = 0.f;
      if ((unsigned)gx < 512u && (unsigned)gy < 512u) {
        size_t o = (size_t)gy * 512 + gx;
        a = x0p[o]; bv = x1p[o];
      }
      Fm[idx] = sqrtf(a * a + bv * bv);
      Sm[idx] = a + bv;
    }
  }
  __syncthreads();
  #pragma unroll
  for (int it = 0; it < 4; ++it) {
    int idx = tid + it * 256;
    if (idx < 864) {
      int r = idx / TWX, c = idx - r * TWX;
      int r1 = (r < 11) ? r + 1 : r;
      int c1 = (c < TWX - 1) ? c + 1 : c;
      float v00 = Fm[r * TWX + c],  v01 = Fm[r * TWX + c1];
      float v10 = Fm[r1 * TWX + c], v11 = Fm[r1 * TWX + c1];
      Qd[idx] = make_float4(v00, v01 - v00, v10 - v00, (v11 - v10) - (v01 - v00));
    }
  }
  __syncthreads();
  const int gi = bx0 + HALO + tx;
  const int gj = by0 + HALO + ty;
  const float SC = (float)(512.0 / 511.0);
  const float axl = fmaf((float)gi, SC, -0.5f) - (float)bx0;
  const float ayl = fmaf((float)gj, SC, -0.5f) - (float)by0;
  float wn[8];
  #pragma unroll
  for (int n = 0; n < 8; ++n) wn[n] = tbl[96 + n];
  float SY = 0.f, CX = 0.f;
  for (int q = 0; q < 24; ++q) {
    const float csx = tbl[48 + q];
    const float ssy = tbl[72 + q];
    float e2 = 0.f;
    #pragma unroll
    for (int n = 0; n < 8; ++n) {
      const float tn = 0.375f * (float)(n + 1);
      float px = fmaf(-csx, tn, axl);
      float py = fmaf(-ssy, tn, ayl);
      int ix = (int)px, iy = (int)py;
      float fx = FRACTF(px), fy = FRACTF(py);
      float4 v = Qd[iy * TWX + ix];
      float s = fmaf(fx * fy, v.w, fmaf(fy, v.z, fmaf(fx, v.y, v.x)));
      e2 = fmaf(wn[n], s, e2);
    }
    float e = EXP2F(e2);
    SY = fmaf(e, tbl[24 + q], SY);
    CX = fmaf(e, tbl[q], CX);
  }
  const int* ti = (const int*)tbl;
  const int cbase = (ty + 1) * TWX + tx + 1;
  float a0 = 0.f, a1 = 0.f, a2 = 0.f, a3 = 0.f;
  if (ti[107] == 0) {
    #pragma unroll
    for (int t2 = 0; t2 < 8; ++t2) {
      a0 = fmaf(Sm[cbase + ti[140 + t2]], tbl[108 + t2], a0);
      a1 = fmaf(Sm[cbase + ti[148 + t2]], tbl[116 + t2], a1);
      a2 = fmaf(Sm[cbase + ti[156 + t2]], tbl[124 + t2], a2);
      a3 = fmaf(Sm[cbase + ti[164 + t2]], tbl[132 + t2], a3);
    }
  } else {
    for (int kj = 0; kj < 7; ++kj)
      for (int ki = 0; ki < 7; ++ki) {
        float s = Sm[(ty + 1 + kj) * TWX + (tx + 1 + ki)];
        int k = kj * 7 + ki;
        a0 = fmaf(s, Wb[k], a0); a1 = fmaf(s, Wb[49 + k], a1);
        a2 = fmaf(s, Wb[98 + k], a2); a3 = fmaf(s, Wb[147 + k], a3);
      }
  }
  const float irt2  = tbl[104];
  const float gamma = tbl[105];
  const float gainc = tbl[106];
  float ov = finish(SY, CX, a0, a1, a2, a3, cen, irt2, gamma, gainc);
  out[((size_t)b * 512 + gj) * 512 + gi] = ov;
}

extern "C" void kernel_launch(void* const* d_in, const int* in_sizes, int n_in,
                              void* d_out, int out_size, void* d_ws, size_t ws_size,
                              hipStream_t stream) {
  const float* x    = (const float*)d_in[0];
  const float* gain = (const float*)d_in[1];
  const float* lrt  = (const float*)d_in[2];
  const float* rlg  = (const float*)d_in[3];
  const float* Wb   = (const float*)d_in[4];
  const float* cen  = (const float*)d_in[5];
  float* tbl = (float*)d_ws;

  gp_setup<<<1, 64, 0, stream>>>(gain, lrt, rlg, Wb, tbl);

  size_t need = 4096 + (size_t)8 * QIH * QIW * sizeof(float4);
  if (ws_size >= need) {
    float4* qimg = (float4*)((char*)d_ws + 4096);
    gp_quad3<<<dim3((QIH * QIW + 255) / 256, 8), 256, 0, stream>>>(x, qimg);
    gp_main6<<<dim3(4096), dim3(256), 0, stream>>>(x, qimg, Wb, cen, tbl, (float*)d_out);
  } else {
    gp_main_fb<<<dim3(8, 128, 8), dim3(64, 4), 0, stream>>>(x, Wb, cen, tbl, (float*)d_out);
  }
}

// Round 7
// 153.756 us; speedup vs baseline: 1.1347x; 1.0387x over previous
//
#include <hip/hip_runtime.h>
#include <math.h>

#define HALO 4
#define TWX 72
#define TWY 12
#define NST (TWX*TWY)   // 864

#if __has_builtin(__builtin_amdgcn_fractf)
#define FRACTF(x) __builtin_amdgcn_fractf(x)
#else
#define FRACTF(x) ((x) - floorf(x))
#endif
#if __has_builtin(__builtin_amdgcn_exp2f)
#define EXP2F(x) __builtin_amdgcn_exp2f(x)
#else
#define EXP2F(x) exp2f(x)
#endif
#if __has_builtin(__builtin_amdgcn_logf)
#define LOG2F(x) __builtin_amdgcn_logf(x)
#else
#define LOG2F(x) log2f(x)
#endif

// tbl layout (floats):
// [0..23] cos_q  [24..47] sin_q  [48..71] cos_q*SC  [72..95] sin_q*SC
// [96..103] wn_norm*log2e  [104] irt*log2e  [105] gamma  [106] gain
// [172] fastconv ok flag (int)  [180..183] per-bank equal weight
__global__ __launch_bounds__(64) void gp_setup(const float* __restrict__ gain,
                                               const float* __restrict__ lrt,
                                               const float* __restrict__ rlg,
                                               const float* __restrict__ Wb,
                                               float* __restrict__ tbl) {
  int t = threadIdx.x;
  __shared__ float wtmp[8];
  if (t < 8) {
    float tn = (float)(t + 1) * 0.375f;
    wtmp[t] = expf(-0.5f * tn * tn);
  }
  if (t < 24) {
    float th = (6.283185307179586f * (float)t) / 24.0f;
    float c = cosf(th), s = sinf(th);
    const float sc = (float)(512.0 / 511.0);
    tbl[t] = c; tbl[24 + t] = s; tbl[48 + t] = c * sc; tbl[72 + t] = s * sc;
  }
  __syncthreads();
  if (t == 0) {
    const float L2E = 1.44269504088896340736f;
    float sum = 0.f;
    for (int n = 0; n < 8; ++n) sum += wtmp[n];
    for (int n = 0; n < 8; ++n) tbl[96 + n] = (wtmp[n] / sum) * L2E;
    float rt = expf(lrt[0]);
    rt = fminf(fmaxf(rt, 0.001f), 2.0f);
    float sg = 1.0f / (1.0f + expf(-rlg[0]));
    float rho = sg * 0.95f + 0.05f;
    tbl[104] = (1.0f / rt) * L2E;
    tbl[105] = 1.0f / (rho + 1e-8f);
    tbl[106] = fmaxf(gain[0], 0.001f);

    // fast-conv verification: expected line-mask pattern (n=4, tol=0.5) +
    // all-equal weights per bank. Falls back to dense 49-tap conv if not.
    const int K0[7] = {14,15,23,24,25,33,34};
    const int K1[7] = {2,9,17,24,31,39,46};
    const int K2[7] = {4,11,17,24,31,37,44};
    const int K3[7] = {19,20,23,24,25,28,29};
    const int* KK[4] = {K0,K1,K2,K3};
    int ok = 1;
    for (int o = 0; o < 4; ++o) {
      float w0v = Wb[o * 49 + KK[o][0]];
      if (w0v == 0.f) ok = 0;
      unsigned long long mask = 0;
      for (int t2 = 0; t2 < 7; ++t2) mask |= 1ull << KK[o][t2];
      for (int k = 0; k < 49; ++k) {
        float w = Wb[o * 49 + k];
        int nz = (w != 0.f);
        int want = (int)((mask >> k) & 1ull);
        if (nz != want) ok = 0;
        if (nz && w != w0v) ok = 0;
      }
      tbl[180 + o] = w0v;
    }
    ((int*)tbl)[172] = ok;
  }
}

__device__ inline float finish(float SY, float CX, float a0, float a1, float a2,
                               float a3, const float* __restrict__ cen,
                               float irt2, float gamma, float gainc) {
  const float TP  = 6.283185307179586f;
  const float PIF = 3.14159265358979323846f;
  const float HP  = 1.57079632679489661923f;
  float hat = atan2f(SY, CX);
  float r1 = hat + TP;
  r1 = (r1 >= TP) ? (r1 - TP) : r1;
  float theta = (r1 >= PIF) ? (r1 - PIF) : r1;
  float dist[4];
  #pragma unroll
  for (int o = 0; o < 4; ++o) {
    float d = theta - cen[o] + HP;
    d -= (d >= PIF) ? PIF : 0.f;
    d += (d < 0.f) ? PIF : 0.f;
    dist[o] = fabsf(d - HP);
  }
  float mn = fminf(fminf(dist[0], dist[1]), fminf(dist[2], dist[3]));
  float m2 = mn * irt2;
  float eo[4], Z = 0.f;
  #pragma unroll
  for (int o = 0; o < 4; ++o) { eo[o] = EXP2F(fmaf(-irt2, dist[o], m2)); Z += eo[o]; }
  float invZ = 1.0f / Z;
  float sh[4], Zs = 0.f;
  #pragma unroll
  for (int o = 0; o < 4; ++o) {
    sh[o] = EXP2F(gamma * LOG2F(fmaf(eo[o], invZ, 1e-12f)));
    Zs += sh[o];
  }
  float wsi = 1.0f / (Zs + 1e-8f);
  return gainc * ((a0 * sh[0] + a1 * sh[1] + a2 * sh[2] + a3 * sh[3]) * wsi);
}

// Single kernel, all-LDS sampling with per-lane quad-register reuse:
// consecutive radii are 0.375px apart -> the bilinear cell changes only
// ~4.3 times per 8-sample ray, and the change-mask is nearly wave-uniform
// (sub-pixel phase drift across 64 lanes is <= 0.125px). Reload the quad
// only when the cell changes: exec-masked ds_read + s_cbranch_execz skip
// cut LDS-pipe work to ~55%, below the 123us all-LDS wall.
__global__ __launch_bounds__(256) void gp_main7(const float* __restrict__ x,
                                                const float* __restrict__ Wb,
                                                const float* __restrict__ cen,
                                                const float* __restrict__ tbl,
                                                float* __restrict__ out) {
  __shared__ float  Fm[NST];
  __shared__ float  Sm[NST];
  __shared__ float4 Qd[NST];

  const int tx = threadIdx.x;           // 0..63 (one wave per pixel row)
  const int ty = threadIdx.y;           // 0..3
  const int tid = ty * 64 + tx;
  const int bx0 = blockIdx.x * 64 - HALO;
  const int by0 = blockIdx.y * 4 - HALO;
  const int b = blockIdx.z;
  const float* __restrict__ x0p = x + (size_t)b * 2 * 512 * 512;
  const float* __restrict__ x1p = x0p + 512 * 512;

  // Stage Fm = |x|, Sm = x0+x1 with zero halo.
  #pragma unroll
  for (int it = 0; it < 4; ++it) {
    int idx = tid + it * 256;
    if (idx < NST) {
      int r = idx / TWX, c = idx - r * TWX;
      int gy = by0 + r, gx = bx0 + c;
      float a = 0.f, bv = 0.f;
      if ((unsigned)gx < 512u && (unsigned)gy < 512u) {
        size_t o = (size_t)gy * 512 + gx;
        a = x0p[o]; bv = x1p[o];
      }
      Fm[idx] = sqrtf(a * a + bv * bv);
      Sm[idx] = a + bv;
    }
  }
  __syncthreads();
  // Pre-differenced quads: s = v.x + fx*v.y + fy*v.z + fx*fy*v.w
  #pragma unroll
  for (int it = 0; it < 4; ++it) {
    int idx = tid + it * 256;
    if (idx < NST) {
      int r = idx / TWX, c = idx - r * TWX;
      int r1 = (r < TWY - 1) ? r + 1 : r;
      int c1 = (c < TWX - 1) ? c + 1 : c;
      float v00 = Fm[r * TWX + c],  v01 = Fm[r * TWX + c1];
      float v10 = Fm[r1 * TWX + c], v11 = Fm[r1 * TWX + c1];
      Qd[idx] = make_float4(v00, v01 - v00, v10 - v00, (v11 - v10) - (v01 - v00));
    }
  }
  __syncthreads();

  const int gi = bx0 + HALO + tx;
  const int gj = by0 + HALO + ty;
  const float SC = (float)(512.0 / 511.0);
  // Local (window-frame) sample coords are > 0 -> (int) trunc == floor.
  const float axl = fmaf((float)gi, SC, -0.5f) - (float)bx0;
  const float ayl = fmaf((float)gj, SC, -0.5f) - (float)by0;

  float wn[8];
  #pragma unroll
  for (int n = 0; n < 8; ++n) wn[n] = tbl[96 + n];   // pre-scaled by log2(e)

  float SY = 0.f, CX = 0.f;
  for (int q = 0; q < 24; ++q) {
    const float cs = tbl[48 + q];   // uniform s_load
    const float sn = tbl[72 + q];
    float e2 = 0.f;
    int offp = -1;
    float4 v = make_float4(0.f, 0.f, 0.f, 0.f);
    #pragma unroll
    for (int n = 0; n < 8; ++n) {
      const float tn = 0.375f * (float)(n + 1);
      float px = fmaf(-cs, tn, axl);
      float py = fmaf(-sn, tn, ayl);
      int ix = (int)px, iy = (int)py;
      float fx = FRACTF(px), fy = FRACTF(py);
      int off = iy * TWX + ix;
      if (off != offp) {            // masked reload only on cell change
        v = Qd[off];
        offp = off;
      }
      float s = fmaf(fy, fmaf(fx, v.w, v.z), fmaf(fx, v.y, v.x));
      e2 = fmaf(wn[n], s, e2);
    }
    float e = EXP2F(e2);
    SY = fmaf(e, tbl[24 + q], SY);
    CX = fmaf(e, tbl[q], CX);
  }

  // Conv: verified line-mask fast path (equal weights, shared center triples),
  // dense 49-tap fallback otherwise. Center at (ty+4, tx+4), stride 72.
  const int* ti = (const int*)tbl;
  const int ccen = (ty + 4) * TWX + tx + 4;
  float a0, a1, a2, a3;
  if (ti[172]) {
    float sCt = Sm[ccen];
    float H3 = (Sm[ccen - 1] + sCt) + Sm[ccen + 1];
    float V3 = (Sm[ccen - TWX] + sCt) + Sm[ccen + TWX];
    a0 = tbl[180] * (H3 + ((Sm[ccen - 75] + Sm[ccen - 74]) + (Sm[ccen + 74] + Sm[ccen + 75])));
    a1 = tbl[181] * (V3 + ((Sm[ccen - 217] + Sm[ccen - 145]) + (Sm[ccen + 145] + Sm[ccen + 217])));
    a2 = tbl[182] * (V3 + ((Sm[ccen - 215] + Sm[ccen - 143]) + (Sm[ccen + 143] + Sm[ccen + 215])));
    a3 = tbl[183] * (H3 + ((Sm[ccen - 70] + Sm[ccen - 69]) + (Sm[ccen + 69] + Sm[ccen + 70])));
  } else {
    a0 = a1 = a2 = a3 = 0.f;
    for (int kj = 0; kj < 7; ++kj)
      for (int ki = 0; ki < 7; ++ki) {
        float s = Sm[(ty + 1 + kj) * TWX + (tx + 1 + ki)];
        int k = kj * 7 + ki;
        a0 = fmaf(s, Wb[k], a0); a1 = fmaf(s, Wb[49 + k], a1);
        a2 = fmaf(s, Wb[98 + k], a2); a3 = fmaf(s, Wb[147 + k], a3);
      }
  }

  const float irt2  = tbl[104];
  const float gamma = tbl[105];
  const float gainc = tbl[106];
  float ov = finish(SY, CX, a0, a1, a2, a3, cen, irt2, gamma, gainc);
  out[((size_t)b * 512 + gj) * 512 + gi] = ov;
}

extern "C" void kernel_launch(void* const* d_in, const int* in_sizes, int n_in,
                              void* d_out, int out_size, void* d_ws, size_t ws_size,
                              hipStream_t stream) {
  const float* x    = (const float*)d_in[0];
  const float* gain = (const float*)d_in[1];
  const float* lrt  = (const float*)d_in[2];
  const float* rlg  = (const float*)d_in[3];
  const float* Wb   = (const float*)d_in[4];
  const float* cen  = (const float*)d_in[5];
  float* tbl = (float*)d_ws;

  gp_setup<<<1, 64, 0, stream>>>(gain, lrt, rlg, Wb, tbl);

  dim3 grid(8, 128, 8);
  dim3 blk(64, 4);
  gp_main7<<<grid, blk, 0, stream>>>(x, Wb, cen, tbl, (float*)d_out);
}

// Round 8
// 151.695 us; speedup vs baseline: 1.1502x; 1.0136x over previous
//
#include <hip/hip_runtime.h>
#include <math.h>

#define HALO 4
#define TWX 72
#define TWY 12
#define NST (TWX*TWY)   // 864
#define QIW 528
#define QIH 520

typedef float f4 __attribute__((ext_vector_type(4)));

#if __has_builtin(__builtin_amdgcn_fractf)
#define FRACTF(x) __builtin_amdgcn_fractf(x)
#else
#define FRACTF(x) ((x) - floorf(x))
#endif
#if __has_builtin(__builtin_amdgcn_exp2f)
#define EXP2F(x) __builtin_amdgcn_exp2f(x)
#else
#define EXP2F(x) exp2f(x)
#endif
#if __has_builtin(__builtin_amdgcn_logf)
#define LOG2F(x) __builtin_amdgcn_logf(x)
#else
#define LOG2F(x) log2f(x)
#endif

// tbl layout (floats):
// [0..23] cos_q  [24..47] sin_q  [48..71] cos_q*SC  [72..95] sin_q*SC
// [96..103] wn_norm*log2e  [104] irt*log2e  [105] gamma  [106] gain
// [172] fastconv ok flag (int)  [180..183] per-bank equal weight
__global__ __launch_bounds__(64) void gp_setup(const float* __restrict__ gain,
                                               const float* __restrict__ lrt,
                                               const float* __restrict__ rlg,
                                               const float* __restrict__ Wb,
                                               float* __restrict__ tbl) {
  int t = threadIdx.x;
  __shared__ float wtmp[8];
  if (t < 8) {
    float tn = (float)(t + 1) * 0.375f;
    wtmp[t] = expf(-0.5f * tn * tn);
  }
  if (t < 24) {
    float th = (6.283185307179586f * (float)t) / 24.0f;
    float c = cosf(th), s = sinf(th);
    const float sc = (float)(512.0 / 511.0);
    tbl[t] = c; tbl[24 + t] = s; tbl[48 + t] = c * sc; tbl[72 + t] = s * sc;
  }
  __syncthreads();
  if (t == 0) {
    const float L2E = 1.44269504088896340736f;
    float sum = 0.f;
    for (int n = 0; n < 8; ++n) sum += wtmp[n];
    for (int n = 0; n < 8; ++n) tbl[96 + n] = (wtmp[n] / sum) * L2E;
    float rt = expf(lrt[0]);
    rt = fminf(fmaxf(rt, 0.001f), 2.0f);
    float sg = 1.0f / (1.0f + expf(-rlg[0]));
    float rho = sg * 0.95f + 0.05f;
    tbl[104] = (1.0f / rt) * L2E;
    tbl[105] = 1.0f / (rho + 1e-8f);
    tbl[106] = fmaxf(gain[0], 0.001f);

    const int K0[7] = {14,15,23,24,25,33,34};
    const int K1[7] = {2,9,17,24,31,39,46};
    const int K2[7] = {4,11,17,24,31,37,44};
    const int K3[7] = {19,20,23,24,25,28,29};
    const int* KK[4] = {K0,K1,K2,K3};
    int ok = 1;
    for (int o = 0; o < 4; ++o) {
      float w0v = Wb[o * 49 + KK[o][0]];
      if (w0v == 0.f) ok = 0;
      unsigned long long mask = 0;
      for (int t2 = 0; t2 < 7; ++t2) mask |= 1ull << KK[o][t2];
      for (int k = 0; k < 49; ++k) {
        float w = Wb[o * 49 + k];
        int nz = (w != 0.f);
        int want = (int)((mask >> k) & 1ull);
        if (nz != want) ok = 0;
        if (nz && w != w0v) ok = 0;
      }
      tbl[180 + o] = w0v;
    }
    ((int*)tbl)[172] = ok;
  }
}

__device__ inline float fmv(const float* __restrict__ x0p, const float* __restrict__ x1p,
                            int Y, int X) {
  int cY = min(max(Y, 0), 511);
  int cX = min(max(X, 0), 511);
  size_t o = (size_t)cY * 512 + cX;
  float a = x0p[o], b = x1p[o];
  float f = sqrtf(a * a + b * b);
  return ((unsigned)X < 512u && (unsigned)Y < 512u) ? f : 0.f;
}

// Fast prepass: 4 pre-differenced quads per thread, vectorized row loads on
// the interior (96% of threads), clamped scalar path on edges. ~BW-bound.
__global__ __launch_bounds__(256) void gp_quadF(const float* __restrict__ x,
                                                f4* __restrict__ qimg) {
  int g = blockIdx.x * 256 + threadIdx.x;
  if (g >= QIH * 132) return;
  int b = blockIdx.y;
  int y = g / 132, xg = g - y * 132;
  int X = xg * 4 - 4, Y = y - 4;
  const float* __restrict__ x0p = x + (size_t)b * 2 * 512 * 512;
  const float* __restrict__ x1p = x0p + 512 * 512;

  float F0[5], F1[5];
  if (X >= 0 && X <= 507 && Y >= 0 && Y <= 510) {
    size_t r0 = (size_t)Y * 512 + X, r1 = r0 + 512;
    f4 a0 = *(const f4*)(x0p + r0); float a4 = x0p[r0 + 4];
    f4 b0 = *(const f4*)(x1p + r0); float b4 = x1p[r0 + 4];
    f4 c0 = *(const f4*)(x0p + r1); float c4 = x0p[r1 + 4];
    f4 d0 = *(const f4*)(x1p + r1); float d4 = x1p[r1 + 4];
    #pragma unroll
    for (int i = 0; i < 4; ++i) {
      F0[i] = sqrtf(a0[i] * a0[i] + b0[i] * b0[i]);
      F1[i] = sqrtf(c0[i] * c0[i] + d0[i] * d0[i]);
    }
    F0[4] = sqrtf(a4 * a4 + b4 * b4);
    F1[4] = sqrtf(c4 * c4 + d4 * d4);
  } else {
    #pragma unroll
    for (int i = 0; i < 5; ++i) {
      F0[i] = fmv(x0p, x1p, Y, X + i);
      F1[i] = fmv(x0p, x1p, Y + 1, X + i);
    }
  }
  f4* dst = qimg + (size_t)(b * QIH + y) * QIW + xg * 4;
  #pragma unroll
  for (int k = 0; k < 4; ++k) {
    float d0 = F0[k + 1] - F0[k];
    f4 q;
    q[0] = F0[k];
    q[1] = d0;
    q[2] = F1[k] - F0[k];
    q[3] = (F1[k + 1] - F1[k]) - d0;
    dst[k] = q;
  }
}

__device__ inline float finish(float SY, float CX, float a0, float a1, float a2,
                               float a3, const float* __restrict__ cen,
                               float irt2, float gamma, float gainc) {
  const float TP  = 6.283185307179586f;
  const float PIF = 3.14159265358979323846f;
  const float HP  = 1.57079632679489661923f;
  float hat = atan2f(SY, CX);
  float r1 = hat + TP;
  r1 = (r1 >= TP) ? (r1 - TP) : r1;
  float theta = (r1 >= PIF) ? (r1 - PIF) : r1;
  float dist[4];
  #pragma unroll
  for (int o = 0; o < 4; ++o) {
    float d = theta - cen[o] + HP;
    d -= (d >= PIF) ? PIF : 0.f;
    d += (d < 0.f) ? PIF : 0.f;
    dist[o] = fabsf(d - HP);
  }
  float mn = fminf(fminf(dist[0], dist[1]), fminf(dist[2], dist[3]));
  float m2 = mn * irt2;
  float eo[4], Z = 0.f;
  #pragma unroll
  for (int o = 0; o < 4; ++o) { eo[o] = EXP2F(fmaf(-irt2, dist[o], m2)); Z += eo[o]; }
  float invZ = 1.0f / Z;
  float sh[4], Zs = 0.f;
  #pragma unroll
  for (int o = 0; o < 4; ++o) {
    sh[o] = EXP2F(gamma * LOG2F(fmaf(eo[o], invZ, 1e-12f)));
    Zs += sh[o];
  }
  float wsi = 1.0f / (Zs + 1e-8f);
  return gainc * ((a0 * sh[0] + a1 * sh[1] + a2 * sh[2] + a3 * sh[3]) * wsi);
}

#define TN0 0.375f
#define TN1 0.75f
#define TN2 1.125f
#define TN3 1.5f
#define TN4 1.875f
#define TN5 2.25f
#define TN6 2.625f
#define TN7 3.0f

// coords for sample n (window frame, coords > 0 so trunc == floor)
#define CRD(n) \
  float px##n = fmaf(-cs, TN##n, axl); \
  float py##n = fmaf(-sn, TN##n, ayl); \
  int   ix##n = (int)px##n; \
  int   iy##n = (int)py##n; \
  float fx##n = FRACTF(px##n); \
  float fy##n = FRACTF(py##n);

#define BILERP(v, n) fmaf(fy##n, fmaf(fx##n, v.w, v.z), fmaf(fx##n, v.y, v.x))
#define BILERP4(v, n) fmaf(fy##n, fmaf(fx##n, v[3], v[2]), fmaf(fx##n, v[1], v[0]))

// Main: radius-split gather. n in {0..4}: LDS quads; n in {5,6,7}: global quad
// image via VMEM (own-XCD L2, swizzled). VMEM issued first, LDS issue+consume
// overlaps their flight, asm keep-alive fences the batch before B-consume.
// Accumulation stays in n-order 0..7 -> bit-identical to proven kernels.
__global__ __launch_bounds__(256) void gp_main8(const float* __restrict__ x,
                                                const f4* __restrict__ qimg,
                                                const float* __restrict__ Wb,
                                                const float* __restrict__ cen,
                                                const float* __restrict__ tbl,
                                                float* __restrict__ out) {
  __shared__ f4    Qd[NST];
  __shared__ float Sm[NST];

  const int tx = threadIdx.x;           // 0..63
  const int ty = threadIdx.y;           // 0..3
  const int tid = ty * 64 + tx;
  int wg = blockIdx.x;
  int swz = (wg & 7) * 1024 + (wg >> 3);   // XCD k -> batch k (4.4MB ~ its L2)
  int bx = swz & 7;
  int by = (swz >> 3) & 127;
  int b  = swz >> 10;

  const int bx0 = bx * 64 - HALO;
  const int by0 = by * 4 - HALO;
  const float* __restrict__ x0p = x + (size_t)b * 2 * 512 * 512;
  const float* __restrict__ x1p = x0p + 512 * 512;
  const f4* __restrict__ qg = qimg + (size_t)(b * QIH + by * 4) * QIW + bx * 64;

  // Stage LDS quad window from the quad image; Sm = x0+x1 with zero halo.
  #pragma unroll
  for (int it = 0; it < 4; ++it) {
    int idx = tid + it * 256;
    if (idx < NST) {
      int r = idx / TWX, c = idx - r * TWX;
      Qd[idx] = qg[r * QIW + c];
    }
  }
  #pragma unroll
  for (int it = 0; it < 4; ++it) {
    int idx = tid + it * 256;
    if (idx < NST) {
      int r = idx / TWX, c = idx - r * TWX;
      int gy = by0 + r, gx = bx0 + c;
      float a = 0.f, bv = 0.f;
      if ((unsigned)gx < 512u && (unsigned)gy < 512u) {
        size_t o = (size_t)gy * 512 + gx;
        a = x0p[o]; bv = x1p[o];
      }
      Sm[idx] = a + bv;
    }
  }
  __syncthreads();

  const int gi = bx0 + HALO + tx;
  const int gj = by0 + HALO + ty;
  const float SC = (float)(512.0 / 511.0);
  const float axl = fmaf((float)gi, SC, -0.5f) - (float)bx0;
  const float ayl = fmaf((float)gj, SC, -0.5f) - (float)by0;

  const float wn0 = tbl[96], wn1 = tbl[97], wn2 = tbl[98], wn3 = tbl[99];
  const float wn4 = tbl[100], wn5 = tbl[101], wn6 = tbl[102], wn7 = tbl[103];

  float SY = 0.f, CX = 0.f;
  for (int q = 0; q < 24; ++q) {
    const float cs = tbl[48 + q];
    const float sn = tbl[72 + q];
    // --- issue the 3 VMEM gathers first (fly under the LDS work) ---
    CRD(5) CRD(6) CRD(7)
    f4 B5 = qg[iy5 * QIW + ix5];
    f4 B6 = qg[iy6 * QIW + ix6];
    f4 B7 = qg[iy7 * QIW + ix7];
    // --- LDS radii 0..4: issue + consume (counted lgkm waits) ---
    CRD(0) CRD(1) CRD(2) CRD(3) CRD(4)
    f4 A0 = Qd[iy0 * TWX + ix0];
    f4 A1 = Qd[iy1 * TWX + ix1];
    f4 A2 = Qd[iy2 * TWX + ix2];
    f4 A3 = Qd[iy3 * TWX + ix3];
    f4 A4 = Qd[iy4 * TWX + ix4];
    float e2 = wn0 * BILERP4(A0, 0);
    e2 = fmaf(wn1, BILERP4(A1, 1), e2);
    e2 = fmaf(wn2, BILERP4(A2, 2), e2);
    e2 = fmaf(wn3, BILERP4(A3, 3), e2);
    e2 = fmaf(wn4, BILERP4(A4, 4), e2);
    // --- fence the VMEM batch, then consume in n-order ---
    asm volatile("" : : "v"(B5), "v"(B6), "v"(B7));
    e2 = fmaf(wn5, BILERP4(B5, 5), e2);
    e2 = fmaf(wn6, BILERP4(B6, 6), e2);
    e2 = fmaf(wn7, BILERP4(B7, 7), e2);

    float e = EXP2F(e2);
    SY = fmaf(e, tbl[24 + q], SY);
    CX = fmaf(e, tbl[q], CX);
  }

  // Conv: verified line-mask fast path (stride 72, halo 4), dense fallback.
  const int* ti = (const int*)tbl;
  const int ccen = (ty + 4) * TWX + tx + 4;
  float a0, a1, a2, a3;
  if (ti[172]) {
    float sCt = Sm[ccen];
    float H3 = (Sm[ccen - 1] + sCt) + Sm[ccen + 1];
    float V3 = (Sm[ccen - TWX] + sCt) + Sm[ccen + TWX];
    a0 = tbl[180] * (H3 + ((Sm[ccen - 75] + Sm[ccen - 74]) + (Sm[ccen + 74] + Sm[ccen + 75])));
    a1 = tbl[181] * (V3 + ((Sm[ccen - 217] + Sm[ccen - 145]) + (Sm[ccen + 145] + Sm[ccen + 217])));
    a2 = tbl[182] * (V3 + ((Sm[ccen - 215] + Sm[ccen - 143]) + (Sm[ccen + 143] + Sm[ccen + 215])));
    a3 = tbl[183] * (H3 + ((Sm[ccen - 70] + Sm[ccen - 69]) + (Sm[ccen + 69] + Sm[ccen + 70])));
  } else {
    a0 = a1 = a2 = a3 = 0.f;
    for (int kj = 0; kj < 7; ++kj)
      for (int ki = 0; ki < 7; ++ki) {
        float s = Sm[(ty + 1 + kj) * TWX + (tx + 1 + ki)];
        int k = kj * 7 + ki;
        a0 = fmaf(s, Wb[k], a0); a1 = fmaf(s, Wb[49 + k], a1);
        a2 = fmaf(s, Wb[98 + k], a2); a3 = fmaf(s, Wb[147 + k], a3);
      }
  }

  const float irt2  = tbl[104];
  const float gamma = tbl[105];
  const float gainc = tbl[106];
  float ov = finish(SY, CX, a0, a1, a2, a3, cen, irt2, gamma, gainc);
  out[((size_t)b * 512 + gj) * 512 + gi] = ov;
}

// Fallback (ws too small): all-LDS single-kernel (R2-equivalent, proven).
__global__ __launch_bounds__(256) void gp_main_fb(const float* __restrict__ x,
                                                  const float* __restrict__ Wb,
                                                  const float* __restrict__ cen,
                                                  const float* __restrict__ tbl,
                                                  float* __restrict__ out) {
  __shared__ float Fm[NST];
  __shared__ float Sm[NST];
  __shared__ f4    Qd[NST];
  const int tx = threadIdx.x;
  const int ty = threadIdx.y;
  const int tid = ty * 64 + tx;
  const int bx0 = blockIdx.x * 64 - HALO;
  const int by0 = blockIdx.y * 4 - HALO;
  const int b = blockIdx.z;
  const float* __restrict__ x0p = x + (size_t)b * 2 * 512 * 512;
  const float* __restrict__ x1p = x0p + 512 * 512;
  #pragma unroll
  for (int it = 0; it < 4; ++it) {
    int idx = tid + it * 256;
    if (idx < NST) {
      int r = idx / TWX, c = idx - r * TWX;
      int gy = by0 + r, gx = bx0 + c;
      float a = 0.f, bv = 0.f;
      if ((unsigned)gx < 512u && (unsigned)gy < 512u) {
        size_t o = (size_t)gy * 512 + gx;
        a = x0p[o]; bv = x1p[o];
      }
      Fm[idx] = sqrtf(a * a + bv * bv);
      Sm[idx] = a + bv;
    }
  }
  __syncthreads();
  #pragma unroll
  for (int it = 0; it < 4; ++it) {
    int idx = tid + it * 256;
    if (idx < NST) {
      int r = idx / TWX, c = idx - r * TWX;
      int r1 = (r < TWY - 1) ? r + 1 : r;
      int c1 = (c < TWX - 1) ? c + 1 : c;
      float v00 = Fm[r * TWX + c],  v01 = Fm[r * TWX + c1];
      float v10 = Fm[r1 * TWX + c], v11 = Fm[r1 * TWX + c1];
      f4 qv; qv[0] = v00; qv[1] = v01 - v00; qv[2] = v10 - v00;
      qv[3] = (v11 - v10) - (v01 - v00);
      Qd[idx] = qv;
    }
  }
  __syncthreads();
  const int gi = bx0 + HALO + tx;
  const int gj = by0 + HALO + ty;
  const float SC = (float)(512.0 / 511.0);
  const float axl = fmaf((float)gi, SC, -0.5f) - (float)bx0;
  const float ayl = fmaf((float)gj, SC, -0.5f) - (float)by0;
  float wn[8];
  #pragma unroll
  for (int n = 0; n < 8; ++n) wn[n] = tbl[96 + n];
  float SY = 0.f, CX = 0.f;
  for (int q = 0; q < 24; ++q) {
    const float csx = tbl[48 + q];
    const float ssy = tbl[72 + q];
    float e2 = 0.f;
    #pragma unroll
    for (int n = 0; n < 8; ++n) {
      const float tn = 0.375f * (float)(n + 1);
      float px = fmaf(-csx, tn, axl);
      float py = fmaf(-ssy, tn, ayl);
      int ix = (int)px, iy = (int)py;
      float fx = FRACTF(px), fy = FRACTF(py);
      f4 v = Qd[iy * TWX + ix];
      float s = fmaf(fy, fmaf(fx, v[3], v[2]), fmaf(fx, v[1], v[0]));
      e2 = fmaf(wn[n], s, e2);
    }
    float e = EXP2F(e2);
    SY = fmaf(e, tbl[24 + q], SY);
    CX = fmaf(e, tbl[q], CX);
  }
  const int* ti = (const int*)tbl;
  const int ccen = (ty + 4) * TWX + tx + 4;
  float a0, a1, a2, a3;
  if (ti[172]) {
    float sCt = Sm[ccen];
    float H3 = (Sm[ccen - 1] + sCt) + Sm[ccen + 1];
    float V3 = (Sm[ccen - TWX] + sCt) + Sm[ccen + TWX];
    a0 = tbl[180] * (H3 + ((Sm[ccen - 75] + Sm[ccen - 74]) + (Sm[ccen + 74] + Sm[ccen + 75])));
    a1 = tbl[181] * (V3 + ((Sm[ccen - 217] + Sm[ccen - 145]) + (Sm[ccen + 145] + Sm[ccen + 217])));
    a2 = tbl[182] * (V3 + ((Sm[ccen - 215] + Sm[ccen - 143]) + (Sm[ccen + 143] + Sm[ccen + 215])));
    a3 = tbl[183] * (H3 + ((Sm[ccen - 70] + Sm[ccen - 69]) + (Sm[ccen + 69] + Sm[ccen + 70])));
  } else {
    a0 = a1 = a2 = a3 = 0.f;
    for (int kj = 0; kj < 7; ++kj)
      for (int ki = 0; ki < 7; ++ki) {
        float s = Sm[(ty + 1 + kj) * TWX + (tx + 1 + ki)];
        int k = kj * 7 + ki;
        a0 = fmaf(s, Wb[k], a0); a1 = fmaf(s, Wb[49 + k], a1);
        a2 = fmaf(s, Wb[98 + k], a2); a3 = fmaf(s, Wb[147 + k], a3);
      }
  }
  const float irt2  = tbl[104];
  const float gamma = tbl[105];
  const float gainc = tbl[106];
  float ov = finish(SY, CX, a0, a1, a2, a3, cen, irt2, gamma, gainc);
  out[((size_t)b * 512 + gj) * 512 + gi] = ov;
}

extern "C" void kernel_launch(void* const* d_in, const int* in_sizes, int n_in,
                              void* d_out, int out_size, void* d_ws, size_t ws_size,
                              hipStream_t stream) {
  const float* x    = (const float*)d_in[0];
  const float* gain = (const float*)d_in[1];
  const float* lrt  = (const float*)d_in[2];
  const float* rlg  = (const float*)d_in[3];
  const float* Wb   = (const float*)d_in[4];
  const float* cen  = (const float*)d_in[5];
  float* tbl = (float*)d_ws;

  gp_setup<<<1, 64, 0, stream>>>(gain, lrt, rlg, Wb, tbl);

  size_t need = 4096 + (size_t)8 * QIH * QIW * sizeof(f4);
  if (ws_size >= need) {
    f4* qimg = (f4*)((char*)d_ws + 4096);
    gp_quadF<<<dim3((QIH * 132 + 255) / 256, 8), 256, 0, stream>>>(x, qimg);
    gp_main8<<<dim3(8192), dim3(64, 4), 0, stream>>>(x, qimg, Wb, cen, tbl, (float*)d_out);
  } else {
    gp_main_fb<<<dim3(8, 128, 8), dim3(64, 4), 0, stream>>>(x, Wb, cen, tbl, (float*)d_out);
  }
}